// Round 4
// baseline (2592.829 us; speedup 1.0000x reference)
//
#include <hip/hip_runtime.h>
#include <math.h>

// Chunked multi-kernel TCN. Grid 2048 = (b, a-group of 64); block 256 =
// 64 a-lanes x 4 d-chunks (16 d each) -> 8 blocks/CU = 32 waves/CU at
// VGPR<=64 (R3 ran 8 waves/CU, latency-bound at VALUBusy 42%).
// Stat kernels + k_prod3 are read-only on their conv input (halo = guarded
// loads). k_prod2 updates base2->base3 in place: all chunks of a column are
// in one block; foreign taps preloaded to regs before __syncthreads.
// t16 tail-fold accumulators are per-(a,chunk) slots, combined in k_tail.
// Base tensor bf16 ushort4 [B][D][A] (64 MiB, coalesced across a).

#define EPS_LN 1e-5f
typedef float4 f4;

__device__ __forceinline__ float gelu_f(float v) {
    // x * sigmoid(1.5957691*(x + 0.044715 x^3)) in exp2 domain, ~6 VALU
    float t = v * fmaf(0.10294324f, v * v, 2.30220822f);
    float e = __builtin_amdgcn_exp2f(-t);
    return v * __builtin_amdgcn_rcpf(1.0f + e);
}

__device__ __forceinline__ void conv4(const f4 a, const f4 c, const f4 e,
                                      const float* __restrict__ wd, float y[4]) {
#pragma unroll
    for (int o = 0; o < 4; ++o) {
        const float* wv = wd + o * 12;
        y[o] = fmaf(a.x, wv[0], fmaf(c.x, wv[1], fmaf(e.x, wv[2],
               fmaf(a.y, wv[3], fmaf(c.y, wv[4], fmaf(e.y, wv[5],
               fmaf(a.z, wv[6], fmaf(c.z, wv[7], fmaf(e.z, wv[8],
               fmaf(a.w, wv[9], fmaf(c.w, wv[10], e.w * wv[11])))))))))));
    }
}

__device__ __forceinline__ unsigned short bf16r(float x) {
    union { float f; unsigned u; } v; v.f = x;
    unsigned r = v.u + 0x7FFFu + ((v.u >> 16) & 1u);   // RNE
    return (unsigned short)(r >> 16);
}
__device__ __forceinline__ float bf16f(unsigned short h) {
    union { float f; unsigned u; } v; v.u = ((unsigned)h) << 16;
    return v.f;
}
__device__ __forceinline__ f4 unpack4(ushort4 p) {
    return make_float4(bf16f(p.x), bf16f(p.y), bf16f(p.z), bf16f(p.w));
}
__device__ __forceinline__ ushort4 pack4(f4 v) {
    ushort4 p; p.x = bf16r(v.x); p.y = bf16r(v.y);
    p.z = bf16r(v.z); p.w = bf16r(v.w); return p;
}

// block(256)=4 waves: reduce (x,y), thread 0 writes pair to gout
__device__ __forceinline__ void red2_out(float x, float y, float* red, int tid,
                                         float* __restrict__ gout) {
#pragma unroll
    for (int off = 32; off > 0; off >>= 1) {
        x += __shfl_down(x, off, 64); y += __shfl_down(y, off, 64);
    }
    const int w = tid >> 6;
    if ((tid & 63) == 0) { red[w] = x; red[4 + w] = y; }
    __syncthreads();
    if (tid == 0) {
        gout[0] = red[0] + red[1] + red[2] + red[3];
        gout[1] = red[4] + red[5] + red[6] + red[7];
    }
}

// block(512)=8 waves: reduce + broadcast (tail kernel)
__device__ __forceinline__ void red2_b8(float& x, float& y, float* red,
                                        float* bc, int tid) {
#pragma unroll
    for (int off = 32; off > 0; off >>= 1) {
        x += __shfl_down(x, off, 64); y += __shfl_down(y, off, 64);
    }
    const int w = tid >> 6;
    if ((tid & 63) == 0) { red[w] = x; red[8 + w] = y; }
    __syncthreads();
    if (tid == 0) {
        float sx = 0.f, sy = 0.f;
#pragma unroll
        for (int i = 0; i < 8; ++i) { sx += red[i]; sy += red[8 + i]; }
        bc[0] = sx; bc[1] = sy;
    }
    __syncthreads();
    x = bc[0]; y = bc[1];
}

#define DECODE_IDX                                   \
    const int tid = threadIdx.x;                     \
    const int b   = blockIdx.x >> 3;                 \
    const int ag  = blockIdx.x & 7;                  \
    const int a   = (ag << 6) | (tid & 63);          \
    const int d0  = (tid >> 6) << 4;                 /* chunk*16, wave-uniform */

__device__ __forceinline__ float sum8(const float* __restrict__ p, int b, int k) {
    float s = 0.f;
#pragma unroll
    for (int g = 0; g < 8; ++g) s += p[(b * 8 + g) * 2 + k];
    return s;
}

// ---- K1: y1 stats from s ----
__global__ __launch_bounds__(256)
void k_stat_s(const float* __restrict__ sIn, const float* __restrict__ wd,
              float* __restrict__ outp) {
    __shared__ float red[8];
    DECODE_IDX
    const f4* s4 = (const f4*)sIn;
    const size_t row = ((size_t)b * 512 + a) * 64;
    const f4 z4 = make_float4(0.f, 0.f, 0.f, 0.f);
    auto ldS = [&](int q) -> f4 { return (q >= 0 && q < 64) ? s4[row + q] : z4; };
    float s1 = 0.f, s2 = 0.f;
    f4 wA = ldS(d0 - 2), wB = ldS(d0 - 1), wC = ldS(d0), wD = ldS(d0 + 1), wE;
#pragma unroll
    for (int j = 0; j < 16; ++j) {
        wE = ldS(d0 + j + 2);
        float y[4]; conv4(wA, wC, wE, wd, y);
#pragma unroll
        for (int o = 0; o < 4; ++o) { s1 += y[o]; s2 = fmaf(y[o], y[o], s2); }
        wA = wB; wB = wC; wC = wD; wD = wE;
    }
    red2_out(s1, s2, red, tid, outp + blockIdx.x * 2);
}

// ---- y-stats from bf16 base (read-only) ----
__global__ __launch_bounds__(256)
void k_stat_b(const ushort4* __restrict__ baseB, const float* __restrict__ wd,
              float* __restrict__ outp) {
    __shared__ float red[8];
    DECODE_IDX
    const size_t col = (size_t)b * 32768 + a;
    const f4 z4 = make_float4(0.f, 0.f, 0.f, 0.f);
    auto ldB = [&](int q) -> f4 {
        return (q >= 0 && q < 64) ? unpack4(baseB[col + (size_t)q * 512]) : z4;
    };
    float s1 = 0.f, s2 = 0.f;
    f4 wA = ldB(d0 - 2), wB = ldB(d0 - 1), wC = ldB(d0), wD = ldB(d0 + 1), wE;
#pragma unroll
    for (int j = 0; j < 16; ++j) {
        wE = ldB(d0 + j + 2);
        float y[4]; conv4(wA, wC, wE, wd, y);
#pragma unroll
        for (int o = 0; o < 4; ++o) { s1 += y[o]; s2 = fmaf(y[o], y[o], s2); }
        wA = wB; wB = wC; wC = wD; wD = wE;
    }
    red2_out(s1, s2, red, tid, outp + blockIdx.x * 2);
}

// ---- K2: x1, base2 = s + x1 (bf16 store), t16 slot init, cs partials ----
__global__ __launch_bounds__(256)
void k_prod1(const float* __restrict__ sIn, const float* __restrict__ w1d,
             const float* __restrict__ w1p, const float* __restrict__ cw,
             const float* __restrict__ c2w, ushort4* __restrict__ baseB,
             float* __restrict__ t16buf, const float* __restrict__ ypIn,
             float* __restrict__ cspOut) {
    __shared__ float red[8];
    DECODE_IDX
    const f4* s4 = (const f4*)sIn;
    const size_t row = ((size_t)b * 512 + a) * 64;
    const size_t col = (size_t)b * 32768 + a;
    const f4 z4 = make_float4(0.f, 0.f, 0.f, 0.f);
    auto ldS = [&](int q) -> f4 { return (q >= 0 && q < 64) ? s4[row + q] : z4; };
    const float NY = 131072.f;
    const float m1 = sum8(ypIn, b, 0) / NY;
    const float q0 = sum8(ypIn, b, 1) / NY;
    const float r1 = rsqrtf(q0 - m1 * m1 + EPS_LN);

    float t16a[16];
#pragma unroll
    for (int o = 0; o < 16; ++o) t16a[o] = 0.f;
    float cs1 = 0.f, cs2 = 0.f;

    f4 wA = ldS(d0 - 2), wB = ldS(d0 - 1), wC = ldS(d0), wD = ldS(d0 + 1), wE;
#pragma unroll
    for (int j = 0; j < 16; ++j) {
        const int e = d0 + j;
        wE = ldS(e + 2);
        float y[4]; conv4(wA, wC, wE, w1d, y);
#pragma unroll
        for (int o = 0; o < 4; ++o) y[o] = (y[o] - m1) * r1;
        float g[4];
#pragma unroll
        for (int o = 0; o < 4; ++o) {
            float zz = fmaf(y[0], w1p[o*4+0], fmaf(y[1], w1p[o*4+1],
                       fmaf(y[2], w1p[o*4+2], y[3] * w1p[o*4+3])));
            g[o] = gelu_f(zz);
            cs1 += g[o]; cs2 = fmaf(g[o], g[o], cs2);
        }
        f4 nb = make_float4(wC.x + g[0], wC.y + g[1], wC.z + g[2], wC.w + g[3]);
        baseB[col + (size_t)e * 512] = pack4(nb);
        float u[4];
#pragma unroll
        for (int co = 0; co < 4; ++co)
            u[co] = fmaf(g[0], cw[co*12+0], fmaf(g[1], cw[co*12+1],
                    fmaf(g[2], cw[co*12+2], g[3] * cw[co*12+3])));
#pragma unroll
        for (int o = 0; o < 16; ++o) {
            const float* p = c2w + o * 256 + e;
            t16a[o] = fmaf(u[0], p[0], fmaf(u[1], p[64],
                      fmaf(u[2], p[128], fmaf(u[3], p[192], t16a[o]))));
        }
        wA = wB; wB = wC; wC = wD; wD = wE;
    }
    float* tp = t16buf + (((size_t)b * 512 + a) * 4 + (size_t)(tid >> 6)) * 16;
#pragma unroll
    for (int o = 0; o < 16; ++o) tp[o] = t16a[o];
    red2_out(cs1, cs2, red, tid, cspOut + blockIdx.x * 2);
}

// ---- K3: x2, base3 = base2 + x2 IN-PLACE; foreign taps preloaded ----
__global__ __launch_bounds__(256)
void k_prod2(ushort4* __restrict__ baseB, const float* __restrict__ wd,
             const float* __restrict__ wp, const float* __restrict__ cw,
             const float* __restrict__ c2w, float* __restrict__ t16buf,
             const float* __restrict__ ypIn, float* __restrict__ cspOut) {
    __shared__ float red[8];
    DECODE_IDX
    const size_t col = (size_t)b * 32768 + a;
    const ushort4 zp = make_ushort4(0, 0, 0, 0);
    auto ldRaw = [&](int q) -> ushort4 {
        return (q >= 0 && q < 64) ? baseB[col + (size_t)q * 512] : zp;
    };
    const float NY = 131072.f;
    const float mS = sum8(ypIn, b, 0) / NY;
    const float q0 = sum8(ypIn, b, 1) / NY;
    const float rS = rsqrtf(q0 - mS * mS + EPS_LN);

    // preload foreign taps BEFORE any block thread writes base3
    ushort4 preL0 = ldRaw(d0 - 2), preL1 = ldRaw(d0 - 1);
    ushort4 preR0 = ldRaw(d0 + 16), preR1 = ldRaw(d0 + 17);
    __syncthreads();

    float t16a[16];
    float* tp = t16buf + (((size_t)b * 512 + a) * 4 + (size_t)(tid >> 6)) * 16;
#pragma unroll
    for (int o = 0; o < 16; ++o) t16a[o] = tp[o];
    float cs1 = 0.f, cs2 = 0.f;

    f4 wA = unpack4(preL0), wB = unpack4(preL1);
    f4 wC = unpack4(ldRaw(d0)), wD = unpack4(ldRaw(d0 + 1)), wE;
#pragma unroll
    for (int j = 0; j < 16; ++j) {
        const int e = d0 + j;
        if (j < 14)      wE = unpack4(ldRaw(e + 2));     // own, read-before-write
        else if (j == 14) wE = unpack4(preR0);
        else              wE = unpack4(preR1);
        float y[4]; conv4(wA, wC, wE, wd, y);
#pragma unroll
        for (int o = 0; o < 4; ++o) y[o] = (y[o] - mS) * rS;
        float g[4];
#pragma unroll
        for (int o = 0; o < 4; ++o) {
            float zz = fmaf(y[0], wp[o*4+0], fmaf(y[1], wp[o*4+1],
                       fmaf(y[2], wp[o*4+2], y[3] * wp[o*4+3])));
            g[o] = gelu_f(zz);
            cs1 += g[o]; cs2 = fmaf(g[o], g[o], cs2);
        }
        f4 nb = make_float4(wC.x + g[0], wC.y + g[1], wC.z + g[2], wC.w + g[3]);
        baseB[col + (size_t)e * 512] = pack4(nb);
        float u[4];
#pragma unroll
        for (int co = 0; co < 4; ++co)
            u[co] = fmaf(g[0], cw[co*12+4], fmaf(g[1], cw[co*12+5],
                    fmaf(g[2], cw[co*12+6], g[3] * cw[co*12+7])));
#pragma unroll
        for (int o = 0; o < 16; ++o) {
            const float* p = c2w + o * 256 + e;
            t16a[o] = fmaf(u[0], p[0], fmaf(u[1], p[64],
                      fmaf(u[2], p[128], fmaf(u[3], p[192], t16a[o]))));
        }
        wA = wB; wB = wC; wC = wD; wD = wE;
    }
#pragma unroll
    for (int o = 0; o < 16; ++o) tp[o] = t16a[o];
    red2_out(cs1, cs2, red, tid, cspOut + blockIdx.x * 2);
}

// ---- K4: x3 from base3 (read-only), t16 RMW, cs partials ----
__global__ __launch_bounds__(256)
void k_prod3(const ushort4* __restrict__ baseB, const float* __restrict__ wd,
             const float* __restrict__ wp, const float* __restrict__ cw,
             const float* __restrict__ c2w, float* __restrict__ t16buf,
             const float* __restrict__ ypIn, float* __restrict__ cspOut) {
    __shared__ float red[8];
    DECODE_IDX
    const size_t col = (size_t)b * 32768 + a;
    const f4 z4 = make_float4(0.f, 0.f, 0.f, 0.f);
    auto ldB = [&](int q) -> f4 {
        return (q >= 0 && q < 64) ? unpack4(baseB[col + (size_t)q * 512]) : z4;
    };
    const float NY = 131072.f;
    const float mS = sum8(ypIn, b, 0) / NY;
    const float q0 = sum8(ypIn, b, 1) / NY;
    const float rS = rsqrtf(q0 - mS * mS + EPS_LN);

    float t16a[16];
    float* tp = t16buf + (((size_t)b * 512 + a) * 4 + (size_t)(tid >> 6)) * 16;
#pragma unroll
    for (int o = 0; o < 16; ++o) t16a[o] = tp[o];
    float cs1 = 0.f, cs2 = 0.f;

    f4 wA = ldB(d0 - 2), wB = ldB(d0 - 1), wC = ldB(d0), wD = ldB(d0 + 1), wE;
#pragma unroll
    for (int j = 0; j < 16; ++j) {
        const int e = d0 + j;
        wE = ldB(e + 2);
        float y[4]; conv4(wA, wC, wE, wd, y);
#pragma unroll
        for (int o = 0; o < 4; ++o) y[o] = (y[o] - mS) * rS;
        float g[4];
#pragma unroll
        for (int o = 0; o < 4; ++o) {
            float zz = fmaf(y[0], wp[o*4+0], fmaf(y[1], wp[o*4+1],
                       fmaf(y[2], wp[o*4+2], y[3] * wp[o*4+3])));
            g[o] = gelu_f(zz);
            cs1 += g[o]; cs2 = fmaf(g[o], g[o], cs2);
        }
        float u[4];
#pragma unroll
        for (int co = 0; co < 4; ++co)
            u[co] = fmaf(g[0], cw[co*12+8], fmaf(g[1], cw[co*12+9],
                    fmaf(g[2], cw[co*12+10], g[3] * cw[co*12+11])));
#pragma unroll
        for (int o = 0; o < 16; ++o) {
            const float* p = c2w + o * 256 + e;
            t16a[o] = fmaf(u[0], p[0], fmaf(u[1], p[64],
                      fmaf(u[2], p[128], fmaf(u[3], p[192], t16a[o]))));
        }
        wA = wB; wB = wC; wC = wD; wD = wE;
    }
#pragma unroll
    for (int o = 0; o < 16; ++o) tp[o] = t16a[o];
    red2_out(cs1, cs2, red, tid, cspOut + blockIdx.x * 2);
}

// ---- K5: tail (chunk-sum t16, concat-LN affine, LN16, c3w+w, LN-A) ----
__global__ __launch_bounds__(512)
void k_tail(const float* __restrict__ wIn, const float* __restrict__ cw,
            const float* __restrict__ c2w, const float* __restrict__ c3w,
            const float* __restrict__ t16buf, const float* __restrict__ csp,
            float* __restrict__ out) {
    __shared__ float red[16];
    __shared__ float bc[2];
    __shared__ float Klds[16];
    const int b = blockIdx.x;
    const int tid = threadIdx.x;          // == a

    if (tid < 16) {
        float k = 0.f;
        for (int co = 0; co < 4; ++co) {
            float csum = 0.f;
            for (int j = 0; j < 12; ++j) csum += cw[co * 12 + j];
            const float* p = c2w + tid * 256 + co * 64;
            float t = 0.f;
            for (int d = 0; d < 64; ++d) t += p[d];
            k = fmaf(csum, t, k);
        }
        Klds[tid] = k;
    }
    __syncthreads();

    float cs1 = 0.f, cs2 = 0.f;
#pragma unroll
    for (int ph = 0; ph < 3; ++ph)
#pragma unroll
        for (int g = 0; g < 8; ++g) {
            cs1 += csp[ph * 4096 + (b * 8 + g) * 2];
            cs2 += csp[ph * 4096 + (b * 8 + g) * 2 + 1];
        }
    const float NC = 393216.f;
    const float mcat = cs1 / NC;
    const float rcat = rsqrtf(cs2 / NC - mcat * mcat + EPS_LN);

    const float* tp = t16buf + ((size_t)b * 512 + tid) * 64;   // 4 chunks x 16
    float tv[16];
    float p1 = 0.f, p2 = 0.f;
#pragma unroll
    for (int o = 0; o < 16; ++o) {
        float T = tp[o] + tp[16 + o] + tp[32 + o] + tp[48 + o];
        float v = rcat * (T - mcat * Klds[o]);
        tv[o] = v; p1 += v; p2 = fmaf(v, v, p2);
    }
    red2_b8(p1, p2, red, bc, tid);
    const float m16 = p1 / 8192.f;
    const float r16 = rsqrtf(p2 / 8192.f - m16 * m16 + EPS_LN);

    float v = wIn[(size_t)b * 512 + tid] * c3w[16];
#pragma unroll
    for (int o = 0; o < 16; ++o) v = fmaf((tv[o] - m16) * r16, c3w[o], v);
    float f1 = v, f2 = v * v;
    red2_b8(f1, f2, red, bc, tid);
    const float mA = f1 / 512.f;
    const float rA = rsqrtf(f2 / 512.f - mA * mA + EPS_LN);

    out[(size_t)b * 512 + tid] = (v - mA) * rA;
}

extern "C" void kernel_launch(void* const* d_in, const int* in_sizes, int n_in,
                              void* d_out, int out_size, void* d_ws, size_t ws_size,
                              hipStream_t stream) {
    const float* s   = (const float*)d_in[0];
    const float* w   = (const float*)d_in[1];
    const float* w1d = (const float*)d_in[2];
    const float* w1p = (const float*)d_in[3];
    const float* w2d = (const float*)d_in[4];
    const float* w2p = (const float*)d_in[5];
    const float* w3d = (const float*)d_in[6];
    const float* w3p = (const float*)d_in[7];
    const float* cw  = (const float*)d_in[8];
    const float* c2w = (const float*)d_in[9];
    const float* c3w = (const float*)d_in[10];

    char* ws = (char*)d_ws;
    ushort4* baseB  = (ushort4*)ws;                              // 64 MiB
    float*   t16buf = (float*)(ws + 67108864);                   // 32 MiB
    float*   stats  = (float*)(ws + 67108864 + 33554432);        // 96 KiB
    float*   y1p = stats;                                        // 4096 f
    float*   y2p = stats + 4096;
    float*   y3p = stats + 8192;
    float*   csp = stats + 12288;                                // 3*4096 f

    dim3 g(2048), blk(256);
    k_stat_s<<<g, blk, 0, stream>>>(s, w1d, y1p);
    k_prod1 <<<g, blk, 0, stream>>>(s, w1d, w1p, cw, c2w, baseB, t16buf, y1p, csp);
    k_stat_b<<<g, blk, 0, stream>>>(baseB, w2d, y2p);
    k_prod2 <<<g, blk, 0, stream>>>(baseB, w2d, w2p, cw, c2w, t16buf, y2p, csp + 4096);
    k_stat_b<<<g, blk, 0, stream>>>(baseB, w3d, y3p);
    k_prod3 <<<g, blk, 0, stream>>>(baseB, w3d, w3p, cw, c2w, t16buf, y3p, csp + 8192);
    k_tail  <<<dim3(256), dim3(512), 0, stream>>>(w, cw, c2w, c3w, t16buf, csp, (float*)d_out);
}